// Round 12
// baseline (32.231 us; speedup 1.0000x reference)
//
#include <hip/hip_runtime.h>
#include <math.h>

// Chamfer loss, B=8, C=3, M=N=4096, fp32 — MFMA, round 12.
//
// sq[m][n] = s2[m] + d2[n] - 2 s.d as a K=16 bf16 GEMM with hi/lo split:
//   A_m = [-2xh,-2xh,-2xl,-2xl | y.. | z.. | s2h,s2l,1,1]   (query rows)
//   B_n = [ xh,  xl,  xh,  xl  | y.. | z.. | 1,1,d2h,d2l]   (reference cols)
// C layout (m74/m101): col = lane&31, row = (reg&3) + 8*(reg>>2) + 4*(lane>>5)
//
// Round-12 = round-10 base (23.0 us, 4 waves/SIMD known-good) + two
// work-per-pair reductions, occupancy untouched:
//   - min3 merge: fwd = min(fwd, min(acc0,acc1)) -> 0.5 min-VALU/pair
//   - 2 row-tiles/wave (afrag0/afrag1): each ds_read_b128 feeds 2 MFMAs
//     -> LDS-read pipe per CU halved (was the largest pipe cost, ~5.1 us)
//   - MFMA order keeps <=3 accs live (~105 VGPR, no spill at lb(256,4))
//   - zero memsets (12B graph memset costs ~11 us), plain stores only
// round-11 lesson: never bundle an occupancy experiment with work changes.

constexpr int B = 8;
constexpr int M = 4096;   // == N

typedef __attribute__((ext_vector_type(8)))  short bf16x8;
typedef __attribute__((ext_vector_type(16))) float f32x16;

__device__ inline unsigned short bf16_of(float x) {   // round-to-nearest-even
    unsigned int u = __float_as_uint(x);
    u += 0x7FFFu + ((u >> 16) & 1u);
    return (unsigned short)(u >> 16);
}
__device__ inline float bf16_to_f(unsigned short h) {
    return __uint_as_float(((unsigned int)h) << 16);
}

__device__ inline bf16x8 make_afrag(const float* qb, int row, int hf) {
    const float x = qb[0 * M + row];
    const float y = qb[1 * M + row];
    const float z = qb[2 * M + row];
    const float s2 = x * x + y * y + z * z;
    const float xhf = bf16_to_f(bf16_of(x));
    const float yhf = bf16_to_f(bf16_of(y));
    const float zhf = bf16_to_f(bf16_of(z));
    // -2*hi exact (pow2 scale of a bf16 value)
    const unsigned short nxh = bf16_of(-2.0f * xhf), nxl = bf16_of(-2.0f * (x - xhf));
    const unsigned short nyh = bf16_of(-2.0f * yhf), nyl = bf16_of(-2.0f * (y - yhf));
    const unsigned short nzh = bf16_of(-2.0f * zhf), nzl = bf16_of(-2.0f * (z - zhf));
    const unsigned short s2h = bf16_of(s2);
    const unsigned short s2l = bf16_of(s2 - bf16_to_f(s2h));
    const unsigned short one = 0x3F80;
    bf16x8 alo, ahi;
    alo[0]=(short)nxh; alo[1]=(short)nxh; alo[2]=(short)nxl; alo[3]=(short)nxl;
    alo[4]=(short)nyh; alo[5]=(short)nyh; alo[6]=(short)nyl; alo[7]=(short)nyl;
    ahi[0]=(short)nzh; ahi[1]=(short)nzh; ahi[2]=(short)nzl; ahi[3]=(short)nzl;
    ahi[4]=(short)s2h; ahi[5]=(short)s2l; ahi[6]=(short)one; ahi[7]=(short)one;
    return hf ? ahi : alo;
}

// ws: part [4 cs][16 db][M] f32 @ 0   (1 MB) ; bsums [256] f32 @ 1 MB

// grid 1024 = (dir<<9 | b<<6 | rg<<2 | cs); 256 thr = 4 waves
// wave w: rows rg*256 + w*64 .. +64 (2 row-tiles) ; cols cs*1024 .. +1024
__global__ __launch_bounds__(256, 4) void chamfer_main(
    const float* __restrict__ src,
    const float* __restrict__ dst,
    float* __restrict__ part)
{
    int bid = blockIdx.x;
    const int cs  = bid & 3;  bid >>= 2;
    const int rg  = bid & 15; bid >>= 4;
    const int b   = bid & 7;  bid >>= 3;
    const int dir = bid;      // 0: rows=src scan dst ; 1: rows=dst scan src

    const float* __restrict__ qry = dir ? dst : src;   // A-side (rows)
    const float* __restrict__ ref = dir ? src : dst;   // B-side (cols)

    const int tid  = threadIdx.x;
    const int wave = tid >> 6;
    const int l31  = tid & 31;
    const int hf   = (tid >> 5) & 1;    // k-group / row-half within wave

    __shared__ __align__(16) unsigned short bstage[2][512][8];  // 16 KB

    // ---- two augmented A fragments (rows base..+31, base+32..+63) ----
    const int rbase = rg * 256 + wave * 64;
    const float* qb = qry + (size_t)b * 3 * M;
    const bf16x8 afrag0 = make_afrag(qb, rbase + l31,      hf);
    const bf16x8 afrag1 = make_afrag(qb, rbase + 32 + l31, hf);

    f32x16 fwd0, fwd1;
#pragma unroll
    for (int r = 0; r < 16; ++r) { fwd0[r] = 3.0e38f; fwd1[r] = 3.0e38f; }

    const f32x16 zero = {};
    const float* rb = ref + (size_t)b * 3 * M + cs * 1024;

    for (int ch = 0; ch < 2; ++ch) {
        __syncthreads();   // previous chunk fully consumed before overwrite
        {
            // stage 512 augmented B cols: 2 consecutive cols per thread
            const int c0 = tid * 2;
            const float2 vx = *reinterpret_cast<const float2*>(&rb[0 * M + ch * 512 + c0]);
            const float2 vy = *reinterpret_cast<const float2*>(&rb[1 * M + ch * 512 + c0]);
            const float2 vz = *reinterpret_cast<const float2*>(&rb[2 * M + ch * 512 + c0]);
            const float xs[2] = {vx.x, vx.y};
            const float ys[2] = {vy.x, vy.y};
            const float zs[2] = {vz.x, vz.y};
#pragma unroll
            for (int k = 0; k < 2; ++k) {
                const float x = xs[k], y = ys[k], z = zs[k];
                const float d2 = x * x + y * y + z * z;
                const unsigned short xh = bf16_of(x), xl = bf16_of(x - bf16_to_f(xh));
                const unsigned short yh = bf16_of(y), yl = bf16_of(y - bf16_to_f(yh));
                const unsigned short zh = bf16_of(z), zl = bf16_of(z - bf16_to_f(zh));
                const unsigned short d2h = bf16_of(d2);
                const unsigned short d2l = bf16_of(d2 - bf16_to_f(d2h));
                const unsigned short one = 0x3F80;
                bf16x8 v0, v1;
                v0[0]=(short)xh; v0[1]=(short)xl; v0[2]=(short)xh; v0[3]=(short)xl;
                v0[4]=(short)yh; v0[5]=(short)yl; v0[6]=(short)yh; v0[7]=(short)yl;
                v1[0]=(short)zh; v1[1]=(short)zl; v1[2]=(short)zh; v1[3]=(short)zl;
                v1[4]=(short)one; v1[5]=(short)one; v1[6]=(short)d2h; v1[7]=(short)d2l;
                *reinterpret_cast<bf16x8*>(&bstage[0][c0 + k][0]) = v0;
                *reinterpret_cast<bf16x8*>(&bstage[1][c0 + k][0]) = v1;
            }
        }
        __syncthreads();

        // 16 col-tiles, 2 per step: 2 ds_read_b128 feed 4 MFMAs (2 row-tiles),
        // 32 v_min3. Order keeps <=3 accs live.
#pragma unroll
        for (int i = 0; i < 8; ++i) {
            const bf16x8 bf0 = *reinterpret_cast<const bf16x8*>(&bstage[hf][i * 64 + l31][0]);
            const bf16x8 bf1 = *reinterpret_cast<const bf16x8*>(&bstage[hf][i * 64 + 32 + l31][0]);
            const f32x16 acc00 = __builtin_amdgcn_mfma_f32_32x32x16_bf16(afrag0, bf0, zero, 0, 0, 0);
            const f32x16 acc10 = __builtin_amdgcn_mfma_f32_32x32x16_bf16(afrag1, bf0, zero, 0, 0, 0);
            const f32x16 acc01 = __builtin_amdgcn_mfma_f32_32x32x16_bf16(afrag0, bf1, zero, 0, 0, 0);
#pragma unroll
            for (int r = 0; r < 16; ++r)
                fwd0[r] = fminf(fwd0[r], fminf(acc00[r], acc01[r]));   // v_min3
            const f32x16 acc11 = __builtin_amdgcn_mfma_f32_32x32x16_bf16(afrag1, bf1, zero, 0, 0, 0);
#pragma unroll
            for (int r = 0; r < 16; ++r)
                fwd1[r] = fminf(fwd1[r], fminf(acc10[r], acc11[r]));   // v_min3
        }
    }

    // butterfly min across the 32-lane col dimension (halves = distinct rows)
#pragma unroll
    for (int r = 0; r < 16; ++r) {
        float v0 = fwd0[r], v1 = fwd1[r];
        v0 = fminf(v0, __shfl_xor(v0, 1));  v1 = fminf(v1, __shfl_xor(v1, 1));
        v0 = fminf(v0, __shfl_xor(v0, 2));  v1 = fminf(v1, __shfl_xor(v1, 2));
        v0 = fminf(v0, __shfl_xor(v0, 4));  v1 = fminf(v1, __shfl_xor(v1, 4));
        v0 = fminf(v0, __shfl_xor(v0, 8));  v1 = fminf(v1, __shfl_xor(v1, 8));
        v0 = fminf(v0, __shfl_xor(v0, 16)); v1 = fminf(v1, __shfl_xor(v1, 16));
        fwd0[r] = v0; fwd1[r] = v1;
    }
    if (l31 == 0) {   // lanes 0 (row-half 0) and 32 (row-half 1)
        float* pf = part + ((size_t)cs * 16 + dir * 8 + b) * M
                  + rbase + hf * 4;
#pragma unroll
        for (int r = 0; r < 16; ++r) {
            const int ro = (r & 3) + 8 * (r >> 2);
            pf[ro]      = fwd0[r];
            pf[32 + ro] = fwd1[r];
        }
    }
}

// 256 blocks x 256 threads: min over the 4 col-splits, sqrt, block-sum -> bsums
__global__ __launch_bounds__(256) void chamfer_reduce(
    const float* __restrict__ part, float* __restrict__ bsums)
{
    const int idx = blockIdx.x * 256 + threadIdx.x;   // [0, 2*B*M)
    const int row = idx & (M - 1);
    const int db  = idx >> 12;                        // dir*8 + b

    const float* p = part + (size_t)db * M + row;
    const float v = fminf(fminf(p[0],              p[(size_t)16 * M]),
                          fminf(p[(size_t)32 * M], p[(size_t)48 * M]));

    float s = sqrtf(fmaxf(v, 0.0f));
#pragma unroll
    for (int off = 32; off > 0; off >>= 1) s += __shfl_down(s, off);
    __shared__ float partial[4];
    if ((threadIdx.x & 63) == 0) partial[threadIdx.x >> 6] = s;
    __syncthreads();
    if (threadIdx.x == 0)
        bsums[blockIdx.x] = partial[0] + partial[1] + partial[2] + partial[3];
}

// 1 block: total, scale, plain-store out[0..2] (no memset needed anywhere)
__global__ __launch_bounds__(256) void chamfer_final(
    const float* __restrict__ bsums, float* __restrict__ out)
{
    float s = bsums[threadIdx.x];
#pragma unroll
    for (int off = 32; off > 0; off >>= 1) s += __shfl_down(s, off);
    __shared__ float partial[4];
    if ((threadIdx.x & 63) == 0) partial[threadIdx.x >> 6] = s;
    __syncthreads();
    if (threadIdx.x == 0) {
        const float tot = (partial[0] + partial[1] + partial[2] + partial[3])
                        * (1.0f / (float)(B * M));   // fwd /(B*M), bwd /(B*N), M==N
        out[0] = tot;
        out[1] = tot;
        out[2] = tot;
    }
}

extern "C" void kernel_launch(void* const* d_in, const int* in_sizes, int n_in,
                              void* d_out, int out_size, void* d_ws, size_t ws_size,
                              hipStream_t stream)
{
    const float* src = (const float*)d_in[0];   // [B,3,M]
    const float* dst = (const float*)d_in[1];   // [B,3,N]
    float* out = (float*)d_out;                 // 3 floats

    float* part  = (float*)d_ws;                          // 1 MB, fully written
    float* bsums = (float*)((char*)d_ws + (1u << 20));    // 256 floats, fully written

    chamfer_main  <<<1024, 256, 0, stream>>>(src, dst, part);
    chamfer_reduce<<<256, 256, 0, stream>>>(part, bsums);
    chamfer_final <<<1, 256, 0, stream>>>(bsums, out);
}

// Round 13
// 23.914 us; speedup vs baseline: 1.3478x; 1.3478x over previous
//
#include <hip/hip_runtime.h>
#include <math.h>

// Chamfer loss, B=8, C=3, M=N=4096, fp32 — MFMA, round 13.
//
// sq[m][n] = s2[m] + d2[n] - 2 s.d as a K=16 bf16 GEMM with hi/lo split:
//   A_m = [-2xh,-2xh,-2xl,-2xl | y.. | z.. | s2h,s2l,1,1]   (query rows)
//   B_n = [ xh,  xl,  xh,  xl  | y.. | z.. | 1,1,d2h,d2l]   (reference cols)
// C layout (m74/m101): col = lane&31, row = (reg&3) + 8*(reg>>2) + 4*(lane>>5)
//
// Round-13 = round-10 base (23.0 us known-good) + ONE change: each
// ds_read_b128 feeds 2 MFMAs via two A-side row-tiles (wave owns 64 rows),
// halving the LDS-read pipe (round-10's largest pipe cost, ~5.1 us/CU).
// Register discipline (rounds 11/12 lesson — both regressed ~9 us from
// VGPR spill): exactly ONE bf + TWO accs live per step, plain E/O min
// (no min3 merge), live set ~96 <= 128 cap at lb(256,4).
// Zero memsets (12B graph memset costs ~11 us), plain stores only.

constexpr int B = 8;
constexpr int M = 4096;   // == N

typedef __attribute__((ext_vector_type(8)))  short bf16x8;
typedef __attribute__((ext_vector_type(16))) float f32x16;

__device__ inline unsigned short bf16_of(float x) {   // round-to-nearest-even
    unsigned int u = __float_as_uint(x);
    u += 0x7FFFu + ((u >> 16) & 1u);
    return (unsigned short)(u >> 16);
}
__device__ inline float bf16_to_f(unsigned short h) {
    return __uint_as_float(((unsigned int)h) << 16);
}

__device__ inline bf16x8 make_afrag(const float* qb, int row, int hf) {
    const float x = qb[0 * M + row];
    const float y = qb[1 * M + row];
    const float z = qb[2 * M + row];
    const float s2 = x * x + y * y + z * z;
    const float xhf = bf16_to_f(bf16_of(x));
    const float yhf = bf16_to_f(bf16_of(y));
    const float zhf = bf16_to_f(bf16_of(z));
    // -2*hi exact (pow2 scale of a bf16 value)
    const unsigned short nxh = bf16_of(-2.0f * xhf), nxl = bf16_of(-2.0f * (x - xhf));
    const unsigned short nyh = bf16_of(-2.0f * yhf), nyl = bf16_of(-2.0f * (y - yhf));
    const unsigned short nzh = bf16_of(-2.0f * zhf), nzl = bf16_of(-2.0f * (z - zhf));
    const unsigned short s2h = bf16_of(s2);
    const unsigned short s2l = bf16_of(s2 - bf16_to_f(s2h));
    const unsigned short one = 0x3F80;
    bf16x8 alo, ahi;
    alo[0]=(short)nxh; alo[1]=(short)nxh; alo[2]=(short)nxl; alo[3]=(short)nxl;
    alo[4]=(short)nyh; alo[5]=(short)nyh; alo[6]=(short)nyl; alo[7]=(short)nyl;
    ahi[0]=(short)nzh; ahi[1]=(short)nzh; ahi[2]=(short)nzl; ahi[3]=(short)nzl;
    ahi[4]=(short)s2h; ahi[5]=(short)s2l; ahi[6]=(short)one; ahi[7]=(short)one;
    return hf ? ahi : alo;
}

// ws: part [4 cs][16 db][M] f32 @ 0   (1 MB) ; bsums [256] f32 @ 1 MB

// grid 1024 = (dir<<9 | b<<6 | rg<<2 | cs); 256 thr = 4 waves
// wave w: rows rg*256 + w*64 .. +64 (2 row-tiles) ; cols cs*1024 .. +1024
__global__ __launch_bounds__(256, 4) void chamfer_main(
    const float* __restrict__ src,
    const float* __restrict__ dst,
    float* __restrict__ part)
{
    int bid = blockIdx.x;
    const int cs  = bid & 3;  bid >>= 2;
    const int rg  = bid & 15; bid >>= 4;
    const int b   = bid & 7;  bid >>= 3;
    const int dir = bid;      // 0: rows=src scan dst ; 1: rows=dst scan src

    const float* __restrict__ qry = dir ? dst : src;   // A-side (rows)
    const float* __restrict__ ref = dir ? src : dst;   // B-side (cols)

    const int tid  = threadIdx.x;
    const int wave = tid >> 6;
    const int l31  = tid & 31;
    const int hf   = (tid >> 5) & 1;    // k-group / row-half within wave

    __shared__ __align__(16) unsigned short bstage[2][1024][8];  // 32 KB

    // ---- two augmented A fragments (rows base..+31, base+32..+63) ----
    const int rbase = rg * 256 + wave * 64;
    const float* qb = qry + (size_t)b * 3 * M;
    const bf16x8 afrag0 = make_afrag(qb, rbase + l31,      hf);
    const bf16x8 afrag1 = make_afrag(qb, rbase + 32 + l31, hf);

    f32x16 fwd0, fwd1;
#pragma unroll
    for (int r = 0; r < 16; ++r) { fwd0[r] = 3.0e38f; fwd1[r] = 3.0e38f; }

    const f32x16 zero = {};
    const float* rb = ref + (size_t)b * 3 * M + cs * 1024;

    // ---- stage all 1024 cols once (single chunk, 2 barriers total) ----
    {
        const int c0 = tid * 4;
        const float4 vx = *reinterpret_cast<const float4*>(&rb[0 * M + c0]);
        const float4 vy = *reinterpret_cast<const float4*>(&rb[1 * M + c0]);
        const float4 vz = *reinterpret_cast<const float4*>(&rb[2 * M + c0]);
        const float xs[4] = {vx.x, vx.y, vx.z, vx.w};
        const float ys[4] = {vy.x, vy.y, vy.z, vy.w};
        const float zs[4] = {vz.x, vz.y, vz.z, vz.w};
#pragma unroll
        for (int k = 0; k < 4; ++k) {
            const float x = xs[k], y = ys[k], z = zs[k];
            const float d2 = x * x + y * y + z * z;
            const unsigned short xh = bf16_of(x), xl = bf16_of(x - bf16_to_f(xh));
            const unsigned short yh = bf16_of(y), yl = bf16_of(y - bf16_to_f(yh));
            const unsigned short zh = bf16_of(z), zl = bf16_of(z - bf16_to_f(zh));
            const unsigned short d2h = bf16_of(d2);
            const unsigned short d2l = bf16_of(d2 - bf16_to_f(d2h));
            const unsigned short one = 0x3F80;
            bf16x8 v0, v1;
            v0[0]=(short)xh; v0[1]=(short)xl; v0[2]=(short)xh; v0[3]=(short)xl;
            v0[4]=(short)yh; v0[5]=(short)yl; v0[6]=(short)yh; v0[7]=(short)yl;
            v1[0]=(short)zh; v1[1]=(short)zl; v1[2]=(short)zh; v1[3]=(short)zl;
            v1[4]=(short)one; v1[5]=(short)one; v1[6]=(short)d2h; v1[7]=(short)d2l;
            *reinterpret_cast<bf16x8*>(&bstage[0][c0 + k][0]) = v0;
            *reinterpret_cast<bf16x8*>(&bstage[1][c0 + k][0]) = v1;
        }
    }
    __syncthreads();

    // 32 col-tiles: per step 1 ds_read_b128 -> 2 MFMAs (2 row-tiles),
    // 32 v_min (independent fwd0/fwd1 chains). Live: bf + acc0 + acc1.
#pragma unroll 4
    for (int i = 0; i < 32; ++i) {
        const bf16x8 bf = *reinterpret_cast<const bf16x8*>(&bstage[hf][i * 32 + l31][0]);
        const f32x16 acc0 = __builtin_amdgcn_mfma_f32_32x32x16_bf16(afrag0, bf, zero, 0, 0, 0);
        const f32x16 acc1 = __builtin_amdgcn_mfma_f32_32x32x16_bf16(afrag1, bf, zero, 0, 0, 0);
#pragma unroll
        for (int r = 0; r < 16; ++r) {
            fwd0[r] = fminf(fwd0[r], acc0[r]);
            fwd1[r] = fminf(fwd1[r], acc1[r]);
        }
    }

    // butterfly min across the 32-lane col dimension (halves = distinct rows)
#pragma unroll
    for (int r = 0; r < 16; ++r) {
        float v0 = fwd0[r], v1 = fwd1[r];
        v0 = fminf(v0, __shfl_xor(v0, 1));  v1 = fminf(v1, __shfl_xor(v1, 1));
        v0 = fminf(v0, __shfl_xor(v0, 2));  v1 = fminf(v1, __shfl_xor(v1, 2));
        v0 = fminf(v0, __shfl_xor(v0, 4));  v1 = fminf(v1, __shfl_xor(v1, 4));
        v0 = fminf(v0, __shfl_xor(v0, 8));  v1 = fminf(v1, __shfl_xor(v1, 8));
        v0 = fminf(v0, __shfl_xor(v0, 16)); v1 = fminf(v1, __shfl_xor(v1, 16));
        fwd0[r] = v0; fwd1[r] = v1;
    }
    if (l31 == 0) {   // lanes 0 (row-half 0) and 32 (row-half 1)
        float* pf = part + ((size_t)cs * 16 + dir * 8 + b) * M
                  + rbase + hf * 4;
#pragma unroll
        for (int r = 0; r < 16; ++r) {
            const int ro = (r & 3) + 8 * (r >> 2);
            pf[ro]      = fwd0[r];
            pf[32 + ro] = fwd1[r];
        }
    }
}

// 256 blocks x 256 threads: min over the 4 col-splits, sqrt, block-sum -> bsums
__global__ __launch_bounds__(256) void chamfer_reduce(
    const float* __restrict__ part, float* __restrict__ bsums)
{
    const int idx = blockIdx.x * 256 + threadIdx.x;   // [0, 2*B*M)
    const int row = idx & (M - 1);
    const int db  = idx >> 12;                        // dir*8 + b

    const float* p = part + (size_t)db * M + row;
    const float v = fminf(fminf(p[0],              p[(size_t)16 * M]),
                          fminf(p[(size_t)32 * M], p[(size_t)48 * M]));

    float s = sqrtf(fmaxf(v, 0.0f));
#pragma unroll
    for (int off = 32; off > 0; off >>= 1) s += __shfl_down(s, off);
    __shared__ float partial[4];
    if ((threadIdx.x & 63) == 0) partial[threadIdx.x >> 6] = s;
    __syncthreads();
    if (threadIdx.x == 0)
        bsums[blockIdx.x] = partial[0] + partial[1] + partial[2] + partial[3];
}

// 1 block: total, scale, plain-store out[0..2] (no memset needed anywhere)
__global__ __launch_bounds__(256) void chamfer_final(
    const float* __restrict__ bsums, float* __restrict__ out)
{
    float s = bsums[threadIdx.x];
#pragma unroll
    for (int off = 32; off > 0; off >>= 1) s += __shfl_down(s, off);
    __shared__ float partial[4];
    if ((threadIdx.x & 63) == 0) partial[threadIdx.x >> 6] = s;
    __syncthreads();
    if (threadIdx.x == 0) {
        const float tot = (partial[0] + partial[1] + partial[2] + partial[3])
                        * (1.0f / (float)(B * M));   // fwd /(B*M), bwd /(B*N), M==N
        out[0] = tot;
        out[1] = tot;
        out[2] = tot;
    }
}

extern "C" void kernel_launch(void* const* d_in, const int* in_sizes, int n_in,
                              void* d_out, int out_size, void* d_ws, size_t ws_size,
                              hipStream_t stream)
{
    const float* src = (const float*)d_in[0];   // [B,3,M]
    const float* dst = (const float*)d_in[1];   // [B,3,N]
    float* out = (float*)d_out;                 // 3 floats

    float* part  = (float*)d_ws;                          // 1 MB, fully written
    float* bsums = (float*)((char*)d_ws + (1u << 20));    // 256 floats, fully written

    chamfer_main  <<<1024, 256, 0, stream>>>(src, dst, part);
    chamfer_reduce<<<256, 256, 0, stream>>>(part, bsums);
    chamfer_final <<<1, 256, 0, stream>>>(bsums, out);
}